// Round 1
// baseline (11164.309 us; speedup 1.0000x reference)
//
#include <hip/hip_runtime.h>

// GRU_8667244003631 — 2-layer bidirectional GRU, B=128 T=1024 IN=128 H=256 OUT=4.
// Strategy:
//   * f16 MFMA for all matmuls (no fp32 MFMA on CDNA4), fp32 accumulate + fp32 gates.
//   * Input projections px = x@w_ih^T + b_ih precomputed per 128-step chunk (full-GPU GEMM).
//   * Recurrence: 16 persistent blocks (2 dirs x 8 batch-slices of 16 rows); w_hh held
//     entirely in registers (96 f16x8 frags/wave); h in LDS; px prefetched one step
//     ahead via global_load_lds double buffer; one __syncthreads per step.
//   * Workspace (~189 MB): f16 weights | hstate | y0 f16 [T][B][512] | px ring f16 [2][128][128][768].

typedef _Float16 f16;
typedef __attribute__((ext_vector_type(8))) _Float16 f16x8;
typedef __attribute__((ext_vector_type(4))) _Float16 f16x4;
typedef __attribute__((ext_vector_type(4))) float f32x4;

#define AS1 __attribute__((address_space(1)))
#define AS3 __attribute__((address_space(3)))

__device__ __forceinline__ void gld_lds16(const void* g, void* l) {
  __builtin_amdgcn_global_load_lds((const AS1 unsigned int*)g,
                                   (AS3 unsigned int*)l, 16, 0, 0);
}

constexpr int BB  = 128;   // batch
constexpr int TT  = 1024;  // seq len
constexpr int INF = 128;   // layer0 input dim
constexpr int HH  = 256;   // hidden
constexpr int G3  = 768;   // 3*H (gate order r,z,n)
constexpr int DD2 = 512;   // 2*H
constexpr int TC  = 128;   // timestep chunk
constexpr int NCH = TT / TC;

__device__ __forceinline__ float sigm(float x) {
  x = fminf(fmaxf(x, -30.f), 30.f);
  return 1.f / (1.f + __expf(-x));
}
__device__ __forceinline__ float tanh_(float x) {
  x = fminf(fmaxf(x, -15.f), 15.f);
  float e = __expf(-2.f * x);
  return (1.f - e) / (1.f + e);
}

// ---------------- weight fp32 -> fp16 ----------------
__global__ void convw(const float* __restrict__ a, const float* __restrict__ b,
                      const float* __restrict__ c, const float* __restrict__ d,
                      f16* __restrict__ oa, f16* __restrict__ ob,
                      f16* __restrict__ oc, f16* __restrict__ od) {
  int i = blockIdx.x * blockDim.x + threadIdx.x;
  int s = gridDim.x * blockDim.x;
  for (int j = i; j < 2 * G3 * INF; j += s) oa[j] = (f16)a[j];
  for (int j = i; j < 2 * G3 * HH;  j += s) ob[j] = (f16)b[j];
  for (int j = i; j < 2 * G3 * DD2; j += s) oc[j] = (f16)c[j];
  for (int j = i; j < 2 * G3 * HH;  j += s) od[j] = (f16)d[j];
}

// ---------------- input-projection GEMM ----------------
// grid (TC, 12, 2), block 256 (4 waves, 2x2).  Writes px[d][i][b][g] (f16, bias folded).
// A rows for M-tile mt are exactly batch rows at timestep t(mt,d,c).
template <int KD, bool AF16>
__global__ __launch_bounds__(256) void px_gemm(const void* __restrict__ Ain,
                                               const f16* __restrict__ W,
                                               const float* __restrict__ bih,
                                               f16* __restrict__ px, int c) {
  __shared__ __align__(16) f16 As[128][40];
  __shared__ __align__(16) f16 Bs[64][40];
  const int d = blockIdx.z, mt = blockIdx.x, nt = blockIdx.y;
  const int t = d ? (TT - 1 - (c * TC + mt)) : (c * TC + mt);
  const int tid = threadIdx.x, lane = tid & 63, w = tid >> 6;
  const int wm = w >> 1, wn = w & 1;
  const f16* Wd = W + (size_t)d * G3 * KD;
  f32x4 acc[4][2];
  const f32x4 zz = {0.f, 0.f, 0.f, 0.f};
#pragma unroll
  for (int mi = 0; mi < 4; ++mi)
#pragma unroll
    for (int ni = 0; ni < 2; ++ni) acc[mi][ni] = zz;

  for (int kb = 0; kb < KD / 32; ++kb) {
    const int k0 = kb * 32;
    if constexpr (AF16) {       // y0 [T][B][512] f16
      const f16* A = (const f16*)Ain;
#pragma unroll
      for (int p = 0; p < 2; ++p) {
        int idx = p * 256 + tid;
        int row = idx >> 2, kc = idx & 3;
        f16x8 v = *(const f16x8*)(A + ((size_t)t * BB + row) * DD2 + k0 + kc * 8);
        *(f16x8*)&As[row][kc * 8] = v;
      }
    } else {                    // data [B][T][128] f32 -> f16
      const float* A = (const float*)Ain;
#pragma unroll
      for (int p = 0; p < 4; ++p) {
        int idx = p * 256 + tid;
        int row = idx >> 3, kc = idx & 7;
        const float* srcp = A + (size_t)row * (TT * INF) + t * INF + k0 + kc * 4;
        float4 v = *(const float4*)srcp;
        f16x4 h4;
        h4[0] = (f16)v.x; h4[1] = (f16)v.y; h4[2] = (f16)v.z; h4[3] = (f16)v.w;
        *(f16x4*)&As[row][kc * 4] = h4;
      }
    }
    {
      int row = tid >> 2, kc = tid & 3;
      f16x8 v = *(const f16x8*)(Wd + (size_t)(nt * 64 + row) * KD + k0 + kc * 8);
      *(f16x8*)&Bs[row][kc * 8] = v;
    }
    __syncthreads();
#pragma unroll
    for (int mi = 0; mi < 4; ++mi) {
      f16x8 av = *(const f16x8*)&As[wm * 64 + mi * 16 + (lane & 15)][(lane >> 4) * 8];
#pragma unroll
      for (int ni = 0; ni < 2; ++ni) {
        f16x8 bv = *(const f16x8*)&Bs[wn * 32 + ni * 16 + (lane & 15)][(lane >> 4) * 8];
        acc[mi][ni] = __builtin_amdgcn_mfma_f32_16x16x32_f16(av, bv, acc[mi][ni], 0, 0, 0);
      }
    }
    __syncthreads();
  }

  float bias[2];
#pragma unroll
  for (int ni = 0; ni < 2; ++ni)
    bias[ni] = bih[d * G3 + nt * 64 + wn * 32 + ni * 16 + (lane & 15)];
  f16* pxd = px + ((size_t)d * TC + mt) * BB * G3;
#pragma unroll
  for (int mi = 0; mi < 4; ++mi)
#pragma unroll
    for (int ni = 0; ni < 2; ++ni)
#pragma unroll
      for (int r = 0; r < 4; ++r) {
        int brow = wm * 64 + mi * 16 + (lane >> 4) * 4 + r;
        int col = nt * 64 + wn * 32 + ni * 16 + (lane & 15);
        pxd[(size_t)brow * G3 + col] = (f16)(acc[mi][ni][r] + bias[ni]);
      }
}

// ---------------- persistent recurrent kernel ----------------
// grid 16 blocks: d = blk>>3, batch slice = (blk&7)*16.  4 waves; wave w owns hidden
// cols [w*64, w*64+64) for all 3 gates.  w_hh resident in registers (bf[3][4][8]).
template <int LAYER>
__global__ __launch_bounds__(256, 1) void recur(const f16* __restrict__ px,
                                                const f16* __restrict__ whh,
                                                const float* __restrict__ bhh,
                                                float* __restrict__ hstate,
                                                f16* __restrict__ y0, int c) {
  __shared__ __align__(16) f16 hbuf[16][264];          // h (f16), +8 pad vs banks
  __shared__ __align__(16) f16 pxbuf[2][16 * G3];      // px double buffer (DMA dest)
  const int d = blockIdx.x >> 3, b0 = (blockIdx.x & 7) * 16;
  const int tid = threadIdx.x, lane = tid & 63, w = tid >> 6;
  const int cl = lane & 15, r0 = (lane >> 4) * 4;

  const f16* wd = whh + (size_t)d * G3 * HH;
  f16x8 bf[3][4][8];  // [gate][coltile][ktile] — resident weights
#pragma unroll
  for (int g = 0; g < 3; ++g)
#pragma unroll
    for (int ct = 0; ct < 4; ++ct)
#pragma unroll
      for (int kt = 0; kt < 8; ++kt) {
        int col = g * HH + w * 64 + ct * 16 + cl;
        int k = kt * 32 + (lane >> 4) * 8;
        bf[g][ct][kt] = *(const f16x8*)(wd + (size_t)col * HH + k);
      }
  float bias[3][4];
#pragma unroll
  for (int g = 0; g < 3; ++g)
#pragma unroll
    for (int ct = 0; ct < 4; ++ct)
      bias[g][ct] = bhh[d * G3 + g * HH + w * 64 + ct * 16 + cl];

  float hreg[4][4];  // fp32 h carried in registers: [coltile][row]
  if (c == 0) {
#pragma unroll
    for (int ct = 0; ct < 4; ++ct)
#pragma unroll
      for (int r = 0; r < 4; ++r) hreg[ct][r] = 0.f;
    for (int j = tid; j < 16 * 264; j += 256) (&hbuf[0][0])[j] = (f16)0.f;
  } else {
#pragma unroll
    for (int ct = 0; ct < 4; ++ct)
#pragma unroll
      for (int r = 0; r < 4; ++r) {
        int row = r0 + r, col = w * 64 + ct * 16 + cl;
        float v = hstate[((size_t)d * BB + b0 + row) * HH + col];
        hreg[ct][r] = v;
        hbuf[row][col] = (f16)v;
      }
  }

  auto dma = [&](int i, int buf) {  // stage px[d][i][b0..b0+15][0..767] (24 KB, contiguous)
    const f16* slab = px + ((size_t)(d * TC + i) * BB + b0) * G3;
#pragma unroll
    for (int j = 0; j < 6; ++j) {
      int o = (w * 6 + j) << 10;
      gld_lds16((const char*)slab + o + lane * 16, (char*)&pxbuf[buf][0] + o);
    }
  };
  dma(0, 0);

  for (int i = 0; i < TC; ++i) {
    __syncthreads();                    // full drain: px[i] DMA done, h writes visible
    if (i + 1 < TC) dma(i + 1, (i + 1) & 1);  // in flight across whole step
    f32x4 acc[3][4];
    const f32x4 zz = {0.f, 0.f, 0.f, 0.f};
#pragma unroll
    for (int g = 0; g < 3; ++g)
#pragma unroll
      for (int ct = 0; ct < 4; ++ct) acc[g][ct] = zz;
#pragma unroll
    for (int kt = 0; kt < 8; ++kt) {
      f16x8 av = *(const f16x8*)&hbuf[cl][kt * 32 + (lane >> 4) * 8];
#pragma unroll
      for (int g = 0; g < 3; ++g)
#pragma unroll
        for (int ct = 0; ct < 4; ++ct)
          acc[g][ct] = __builtin_amdgcn_mfma_f32_16x16x32_f16(av, bf[g][ct][kt], acc[g][ct], 0, 0, 0);
    }
    __builtin_amdgcn_sched_barrier(0);
    __builtin_amdgcn_s_barrier();       // raw barrier: all waves done reading hbuf (no vmcnt drain)
    __builtin_amdgcn_sched_barrier(0);
    const f16* pxl = &pxbuf[i & 1][0];
#pragma unroll
    for (int ct = 0; ct < 4; ++ct)
#pragma unroll
      for (int r = 0; r < 4; ++r) {
        int row = r0 + r, col = w * 64 + ct * 16 + cl;
        float xr = (float)pxl[row * G3 + col];
        float xz = (float)pxl[row * G3 + HH + col];
        float xn = (float)pxl[row * G3 + 2 * HH + col];
        float rg = sigm(xr + acc[0][ct][r] + bias[0][ct]);
        float zg = sigm(xz + acc[1][ct][r] + bias[1][ct]);
        float ng = tanh_(xn + rg * (acc[2][ct][r] + bias[2][ct]));
        float hv = (1.f - zg) * ng + zg * hreg[ct][r];
        hreg[ct][r] = hv;
        hbuf[row][col] = (f16)hv;
        if constexpr (LAYER == 0) {
          int tphys = d ? (TT - 1 - (c * TC + i)) : (c * TC + i);
          y0[((size_t)tphys * BB + b0 + row) * DD2 + d * HH + col] = (f16)hv;
        }
      }
  }
#pragma unroll
  for (int ct = 0; ct < 4; ++ct)
#pragma unroll
    for (int r = 0; r < 4; ++r)
      hstate[((size_t)d * BB + b0 + r0 + r) * HH + w * 64 + ct * 16 + cl] = hreg[ct][r];
}

// ---------------- output head ----------------
__global__ void head(const float* __restrict__ hstate, const float* __restrict__ wout,
                     const float* __restrict__ bout, float* __restrict__ out) {
  int g = blockIdx.x * blockDim.x + threadIdx.x;  // 0..511
  if (g >= BB * 4) return;
  int b = g >> 2, o = g & 3;
  float s = bout[o];
  for (int jj = 0; jj < DD2; ++jj) {
    int dd = jj >> 8, j = jj & 255;
    s += hstate[((size_t)dd * BB + b) * HH + j] * wout[o * DD2 + jj];
  }
  out[g] = s;
}

extern "C" void kernel_launch(void* const* d_in, const int* in_sizes, int n_in,
                              void* d_out, int out_size, void* d_ws, size_t ws_size,
                              hipStream_t stream) {
  const float* data = (const float*)d_in[0];
  const float* wih0 = (const float*)d_in[1];
  const float* whh0 = (const float*)d_in[2];
  const float* bih0 = (const float*)d_in[3];
  const float* bhh0 = (const float*)d_in[4];
  const float* wih1 = (const float*)d_in[5];
  const float* whh1 = (const float*)d_in[6];
  const float* bih1 = (const float*)d_in[7];
  const float* bhh1 = (const float*)d_in[8];
  const float* wout = (const float*)d_in[9];
  const float* bout = (const float*)d_in[10];

  char* ws = (char*)d_ws;
  f16*   f_wih0 = (f16*)(ws + 0);          //  393216 B
  f16*   f_whh0 = (f16*)(ws + 393216);     //  786432 B
  f16*   f_wih1 = (f16*)(ws + 1179648);    // 1572864 B
  f16*   f_whh1 = (f16*)(ws + 2752512);    //  786432 B
  float* hstate = (float*)(ws + 3538944);  //  262144 B
  f16*   y0     = (f16*)(ws + 4194304);    // 134217728 B  [T][B][512]
  f16*   px     = (f16*)(ws + 138412032);  //  50331648 B  [2][TC][B][768]
  // total 188743680 B

  convw<<<512, 256, 0, stream>>>(wih0, whh0, wih1, whh1, f_wih0, f_whh0, f_wih1, f_whh1);

  dim3 gg(TC, 12, 2);
  for (int c = 0; c < NCH; ++c) {
    px_gemm<INF, false><<<gg, 256, 0, stream>>>(data, f_wih0, bih0, px, c);
    recur<0><<<16, 256, 0, stream>>>(px, f_whh0, bhh0, hstate, y0, c);
  }
  for (int c = 0; c < NCH; ++c) {
    px_gemm<DD2, true><<<gg, 256, 0, stream>>>(y0, f_wih1, bih1, px, c);
    recur<1><<<16, 256, 0, stream>>>(px, f_whh1, bhh1, hstate, nullptr, c);
  }
  head<<<4, 128, 0, stream>>>(hstate, wout, bout, (float*)d_out);
}

// Round 3
// 6109.993 us; speedup vs baseline: 1.8272x; 1.8272x over previous
//
#include <hip/hip_runtime.h>

// GRU_8667244003631 — 2-layer bidirectional GRU, B=128 T=1024 IN=128 H=256 OUT=4.
// Round 2 (resubmit — round-2 bench hit GPUAcquisitionTimeout, never measured):
//   * recur: 512 threads (8 waves), wave owns 32 hidden cols -> w_hh resident in
//     192 VGPR/wave (round-1 spilled at 384). __launch_bounds__(512,2).
//   * hbuf double-buffered [2][16][256] f16 with T2 XOR swizzle ((row&7)<<4):
//     conflict-free b128 A-frag reads + h writes; ONE barrier per step (raw
//     s_barrier + lgkmcnt(0) drain, no vmcnt stall on y0 stores).
//   * px staged to REGISTERS, not LDS: px_gemm writes a consumer-lane-major
//     layout (24 f16 = 48 B contiguous per recur thread) -> 3x b128 global
//     loads per thread per step, hidden under the MFMA phase.
//   * b_hh folded into px for r,z gates (n gate keeps separate bias).

typedef _Float16 f16;
typedef __attribute__((ext_vector_type(8))) _Float16 f16x8;
typedef __attribute__((ext_vector_type(4))) _Float16 f16x4;
typedef __attribute__((ext_vector_type(4))) float f32x4;

constexpr int BB  = 128;   // batch
constexpr int TT  = 1024;  // seq len
constexpr int INF = 128;   // layer0 input dim
constexpr int HH  = 256;   // hidden
constexpr int G3  = 768;   // 3*H (gate order r,z,n)
constexpr int DD2 = 512;   // 2*H
constexpr int TC  = 128;   // timestep chunk
constexpr int NCH = TT / TC;
constexpr int SLAB = 16 * G3;  // f16 per (dir,step,16-row slice) px slab = 24576 B

__device__ __forceinline__ float sigm(float x) {
  // saturates naturally: exp2(+inf)->inf -> rcp -> 0 ; exp2(-inf)->0 -> 1
  float e = __builtin_amdgcn_exp2f(-1.44269504f * x);
  return __builtin_amdgcn_rcpf(1.f + e);
}
__device__ __forceinline__ float tanh_(float x) {
  // tanh(x) = 1 - 2/(1+exp2(2.885x)) ; saturates to +/-1 naturally
  float e = __builtin_amdgcn_exp2f(2.88539009f * x);
  return 1.f - 2.f * __builtin_amdgcn_rcpf(1.f + e);
}

// ---------------- weight fp32 -> fp16 ----------------
__global__ void convw(const float* __restrict__ a, const float* __restrict__ b,
                      const float* __restrict__ c, const float* __restrict__ d,
                      f16* __restrict__ oa, f16* __restrict__ ob,
                      f16* __restrict__ oc, f16* __restrict__ od) {
  int i = blockIdx.x * blockDim.x + threadIdx.x;
  int s = gridDim.x * blockDim.x;
  for (int j = i; j < 2 * G3 * INF; j += s) oa[j] = (f16)a[j];
  for (int j = i; j < 2 * G3 * HH;  j += s) ob[j] = (f16)b[j];
  for (int j = i; j < 2 * G3 * DD2; j += s) oc[j] = (f16)c[j];
  for (int j = i; j < 2 * G3 * HH;  j += s) od[j] = (f16)d[j];
}

// ---------------- input-projection GEMM ----------------
// grid (TC, 12, 2), block 256 (4 waves, 2x2).  Writes px in consumer-lane-major
// slabs: slab (d,step,slice16) of 16x768 f16; within slab, offset =
// (w*64 + hi*16 + cl)*24 + (g*2+ct)*4 + r   [consumer thread's 24 f16 contiguous]
// Bias: b_ih (+ b_hh for r,z gates) folded in here.
template <int KD, bool AF16>
__global__ __launch_bounds__(256) void px_gemm(const void* __restrict__ Ain,
                                               const f16* __restrict__ W,
                                               const float* __restrict__ bih,
                                               const float* __restrict__ bhh,
                                               f16* __restrict__ px, int c) {
  __shared__ __align__(16) f16 As[128][40];
  __shared__ __align__(16) f16 Bs[64][40];
  const int d = blockIdx.z, mt = blockIdx.x, nt = blockIdx.y;
  const int t = d ? (TT - 1 - (c * TC + mt)) : (c * TC + mt);
  const int tid = threadIdx.x, lane = tid & 63, w = tid >> 6;
  const int wm = w >> 1, wn = w & 1;
  const f16* Wd = W + (size_t)d * G3 * KD;
  f32x4 acc[4][2];
  const f32x4 zz = {0.f, 0.f, 0.f, 0.f};
#pragma unroll
  for (int mi = 0; mi < 4; ++mi)
#pragma unroll
    for (int ni = 0; ni < 2; ++ni) acc[mi][ni] = zz;

  for (int kb = 0; kb < KD / 32; ++kb) {
    const int k0 = kb * 32;
    if constexpr (AF16) {       // y0 [T][B][512] f16
      const f16* A = (const f16*)Ain;
#pragma unroll
      for (int p = 0; p < 2; ++p) {
        int idx = p * 256 + tid;
        int row = idx >> 2, kc = idx & 3;
        f16x8 v = *(const f16x8*)(A + ((size_t)t * BB + row) * DD2 + k0 + kc * 8);
        *(f16x8*)&As[row][kc * 8] = v;
      }
    } else {                    // data [B][T][128] f32 -> f16
      const float* A = (const float*)Ain;
#pragma unroll
      for (int p = 0; p < 4; ++p) {
        int idx = p * 256 + tid;
        int row = idx >> 3, kc = idx & 7;
        const float* srcp = A + (size_t)row * (TT * INF) + t * INF + k0 + kc * 4;
        float4 v = *(const float4*)srcp;
        f16x4 h4;
        h4[0] = (f16)v.x; h4[1] = (f16)v.y; h4[2] = (f16)v.z; h4[3] = (f16)v.w;
        *(f16x4*)&As[row][kc * 4] = h4;
      }
    }
    {
      int row = tid >> 2, kc = tid & 3;
      f16x8 v = *(const f16x8*)(Wd + (size_t)(nt * 64 + row) * KD + k0 + kc * 8);
      *(f16x8*)&Bs[row][kc * 8] = v;
    }
    __syncthreads();
#pragma unroll
    for (int mi = 0; mi < 4; ++mi) {
      f16x8 av = *(const f16x8*)&As[wm * 64 + mi * 16 + (lane & 15)][(lane >> 4) * 8];
#pragma unroll
      for (int ni = 0; ni < 2; ++ni) {
        f16x8 bv = *(const f16x8*)&Bs[wn * 32 + ni * 16 + (lane & 15)][(lane >> 4) * 8];
        acc[mi][ni] = __builtin_amdgcn_mfma_f32_16x16x32_f16(av, bv, acc[mi][ni], 0, 0, 0);
      }
    }
    __syncthreads();
  }

  float bias[2];
#pragma unroll
  for (int ni = 0; ni < 2; ++ni) {
    int col = nt * 64 + wn * 32 + ni * 16 + (lane & 15);
    bias[ni] = bih[d * G3 + col] + (col < 2 * HH ? bhh[d * G3 + col] : 0.f);
  }
#pragma unroll
  for (int mi = 0; mi < 4; ++mi)
#pragma unroll
    for (int ni = 0; ni < 2; ++ni)
#pragma unroll
      for (int r = 0; r < 4; ++r) {
        int brow = wm * 64 + mi * 16 + (lane >> 4) * 4 + r;
        int col = nt * 64 + wn * 32 + ni * 16 + (lane & 15);
        int g = col >> 8, ch = col & 255;
        size_t slab = (size_t)((d * TC + mt) * 8 + (brow >> 4)) * SLAB;
        int off = ((ch >> 5) * 64 + ((brow & 15) >> 2) * 16 + (ch & 15)) * 24 +
                  (g * 2 + ((ch >> 4) & 1)) * 4 + (brow & 3);
        px[slab + off] = (f16)(acc[mi][ni][r] + bias[ni]);
      }
}

// ---------------- persistent recurrent kernel ----------------
// grid 16 blocks: d = blk>>3, batch slice = (blk&7)*16.  8 waves; wave w owns
// hidden cols [w*32, w*32+32) for all 3 gates.  w_hh resident: bf[3][2][8] = 192 VGPR.
template <int LAYER>
__global__ __launch_bounds__(512, 2) void recur(const f16* __restrict__ px,
                                                const f16* __restrict__ whh,
                                                const float* __restrict__ bhh,
                                                float* __restrict__ hstate,
                                                f16* __restrict__ y0, int c) {
  __shared__ __align__(16) f16 hbuf[2][16 * 256];  // double-buffered h, XOR-swizzled
  const int d = blockIdx.x >> 3, b0 = (blockIdx.x & 7) * 16;
  const int tid = threadIdx.x, lane = tid & 63, w = tid >> 6;
  const int cl = lane & 15, hi = lane >> 4, r0 = hi * 4;

  const f16* wd = whh + (size_t)d * G3 * HH;
  f16x8 bf[3][2][8];  // [gate][coltile][ktile] — resident weights, 192 VGPR
#pragma unroll
  for (int g = 0; g < 3; ++g)
#pragma unroll
    for (int ct = 0; ct < 2; ++ct)
#pragma unroll
      for (int kt = 0; kt < 8; ++kt) {
        int col = g * HH + w * 32 + ct * 16 + cl;
        int k = kt * 32 + hi * 8;
        bf[g][ct][kt] = *(const f16x8*)(wd + (size_t)col * HH + k);
      }
  float bn[2];  // b_hh for n gate only (r,z folded into px)
#pragma unroll
  for (int ct = 0; ct < 2; ++ct)
    bn[ct] = bhh[d * G3 + 2 * HH + w * 32 + ct * 16 + cl];

  float hreg[2][4];  // fp32 h master state: [coltile][row]
  if (c == 0) {
#pragma unroll
    for (int ct = 0; ct < 2; ++ct)
#pragma unroll
      for (int r = 0; r < 4; ++r) hreg[ct][r] = 0.f;
    for (int j = tid; j < 16 * 256; j += 512) hbuf[0][j] = (f16)0.f;
  } else {
#pragma unroll
    for (int ct = 0; ct < 2; ++ct)
#pragma unroll
      for (int r = 0; r < 4; ++r) {
        int row = r0 + r, col = w * 32 + ct * 16 + cl;
        float v = hstate[((size_t)d * BB + b0 + row) * HH + col];
        hreg[ct][r] = v;
        *(f16*)((char*)&hbuf[0][0] + row * 512 + ((col * 2) ^ ((row & 7) << 4))) = (f16)v;
      }
  }

  // per-step px pointer (consumer-lane-major: this thread's 24 f16 contiguous)
  const f16* pp = px + (size_t)(d * TC * 8 + (b0 >> 4)) * SLAB + (size_t)(w * 64 + lane) * 24;
  // y0 pointer walks physical time
  f16* yp = nullptr;
  ptrdiff_t ystep = 0;
  if constexpr (LAYER == 0) {
    int t0 = d ? (TT - 1 - c * TC) : (c * TC);
    yp = y0 + ((size_t)t0 * BB + b0) * DD2 + d * HH;
    ystep = d ? -(ptrdiff_t)(BB * DD2) : (ptrdiff_t)(BB * DD2);
  }

  for (int i = 0; i < TC; ++i) {
    // one barrier per step: prev epilogue's hbuf writes drained (lgkm only —
    // no vmcnt(0) stall on outstanding y0 stores)
    asm volatile("s_waitcnt lgkmcnt(0)" ::: "memory");
    __builtin_amdgcn_sched_barrier(0);
    __builtin_amdgcn_s_barrier();
    __builtin_amdgcn_sched_barrier(0);

    // issue px loads for this step early; consumed after MFMA phase
    f16x8 p0 = *(const f16x8*)(pp);
    f16x8 p1 = *(const f16x8*)(pp + 8);
    f16x8 p2 = *(const f16x8*)(pp + 16);
    pp += 8 * SLAB;

    const char* hb = (const char*)&hbuf[i & 1][0];
    f32x4 acc[3][2];
    const f32x4 zz = {0.f, 0.f, 0.f, 0.f};
#pragma unroll
    for (int g = 0; g < 3; ++g)
#pragma unroll
      for (int ct = 0; ct < 2; ++ct) acc[g][ct] = zz;
#pragma unroll
    for (int kt = 0; kt < 8; ++kt) {
      const f16x8 av = *(const f16x8*)(hb + cl * 512 + ((kt * 64 + hi * 16) ^ ((cl & 7) << 4)));
#pragma unroll
      for (int g = 0; g < 3; ++g)
#pragma unroll
        for (int ct = 0; ct < 2; ++ct)
          acc[g][ct] = __builtin_amdgcn_mfma_f32_16x16x32_f16(av, bf[g][ct][kt], acc[g][ct], 0, 0, 0);
    }

    // epilogue writes the OTHER h buffer — no read/write hazard, no 2nd barrier
    char* hn = (char*)&hbuf[(i + 1) & 1][0];
#pragma unroll
    for (int ct = 0; ct < 2; ++ct)
#pragma unroll
      for (int r = 0; r < 4; ++r) {
        int row = r0 + r, col = w * 32 + ct * 16 + cl;
        float xr = (float)p0[ct * 4 + r];
        float xz = (float)p1[ct * 4 + r];
        float xn = (float)p2[ct * 4 + r];
        float rg = sigm(xr + acc[0][ct][r]);
        float zg = sigm(xz + acc[1][ct][r]);
        float ng = tanh_(xn + rg * (acc[2][ct][r] + bn[ct]));
        float hv = ng + zg * (hreg[ct][r] - ng);
        hreg[ct][r] = hv;
        *(f16*)(hn + row * 512 + ((col * 2) ^ ((row & 7) << 4))) = (f16)hv;
        if constexpr (LAYER == 0) yp[(size_t)row * DD2 + col] = (f16)hv;
      }
    if constexpr (LAYER == 0) yp += ystep;
  }
#pragma unroll
  for (int ct = 0; ct < 2; ++ct)
#pragma unroll
    for (int r = 0; r < 4; ++r)
      hstate[((size_t)d * BB + b0 + r0 + r) * HH + w * 32 + ct * 16 + cl] = hreg[ct][r];
}

// ---------------- output head ----------------
__global__ void head(const float* __restrict__ hstate, const float* __restrict__ wout,
                     const float* __restrict__ bout, float* __restrict__ out) {
  int g = blockIdx.x * blockDim.x + threadIdx.x;  // 0..511
  if (g >= BB * 4) return;
  int b = g >> 2, o = g & 3;
  float s = bout[o];
  for (int jj = 0; jj < DD2; ++jj) {
    int dd = jj >> 8, j = jj & 255;
    s += hstate[((size_t)dd * BB + b) * HH + j] * wout[o * DD2 + jj];
  }
  out[g] = s;
}

extern "C" void kernel_launch(void* const* d_in, const int* in_sizes, int n_in,
                              void* d_out, int out_size, void* d_ws, size_t ws_size,
                              hipStream_t stream) {
  const float* data = (const float*)d_in[0];
  const float* wih0 = (const float*)d_in[1];
  const float* whh0 = (const float*)d_in[2];
  const float* bih0 = (const float*)d_in[3];
  const float* bhh0 = (const float*)d_in[4];
  const float* wih1 = (const float*)d_in[5];
  const float* whh1 = (const float*)d_in[6];
  const float* bih1 = (const float*)d_in[7];
  const float* bhh1 = (const float*)d_in[8];
  const float* wout = (const float*)d_in[9];
  const float* bout = (const float*)d_in[10];

  char* ws = (char*)d_ws;
  f16*   f_wih0 = (f16*)(ws + 0);          //  393216 B
  f16*   f_whh0 = (f16*)(ws + 393216);     //  786432 B
  f16*   f_wih1 = (f16*)(ws + 1179648);    // 1572864 B
  f16*   f_whh1 = (f16*)(ws + 2752512);    //  786432 B
  float* hstate = (float*)(ws + 3538944);  //  262144 B
  f16*   y0     = (f16*)(ws + 4194304);    // 134217728 B  [T][B][512]
  f16*   px     = (f16*)(ws + 138412032);  //  50331648 B  [2][TC][8 slabs][16*768]
  // total 188743680 B

  convw<<<512, 256, 0, stream>>>(wih0, whh0, wih1, whh1, f_wih0, f_whh0, f_wih1, f_whh1);

  dim3 gg(TC, 12, 2);
  for (int c = 0; c < NCH; ++c) {
    px_gemm<INF, false><<<gg, 256, 0, stream>>>(data, f_wih0, bih0, bhh0, px, c);
    recur<0><<<16, 512, 0, stream>>>(px, f_whh0, bhh0, hstate, y0, c);
  }
  for (int c = 0; c < NCH; ++c) {
    px_gemm<DD2, true><<<gg, 256, 0, stream>>>(y0, f_wih1, bih1, bhh1, px, c);
    recur<1><<<16, 512, 0, stream>>>(px, f_whh1, bhh1, hstate, nullptr, c);
  }
  head<<<4, 128, 0, stream>>>(hstate, wout, bout, (float*)d_out);
}

// Round 4
// 4352.411 us; speedup vs baseline: 2.5651x; 1.4038x over previous
//
#include <hip/hip_runtime.h>

// GRU_8667244003631 — 2-layer bidirectional GRU, B=128 T=1024 IN=128 H=256 OUT=4.
// Round 4: VALU/stall diet on recur (round-3: step=6900cy = 1860 MFMA + 2470 VALU + 2600 stall).
//   * px pre-scaled at GEMM: r,z cols store -1.4427*(x+b_ih+b_hh); n cols store 2.885*(x+b_ih).
//     b_hh_n folded into MFMA acc init -> epilogue is fma/exp2/rcp-only.
//   * LDS swizzle moved to byte-bits 4-5 only ((row&3)<<4): every ds_read/ds_write address is
//     one persistent VGPR + compile-time immediate (incl. double-buffer offset via 2-step unroll).
//     Cost: A-frag reads spread over 4 bank groups (~2x min cycles) — hidden under MFMA phase.
//   * 3-deep rotating prefetch of A-fragments kills per-kt ds_read->MFMA latency stalls.

typedef _Float16 f16;
typedef __attribute__((ext_vector_type(8))) _Float16 f16x8;
typedef __attribute__((ext_vector_type(4))) _Float16 f16x4;
typedef __attribute__((ext_vector_type(4))) float f32x4;

constexpr int BB  = 128;   // batch
constexpr int TT  = 1024;  // seq len
constexpr int INF = 128;   // layer0 input dim
constexpr int HH  = 256;   // hidden
constexpr int G3  = 768;   // 3*H (gate order r,z,n)
constexpr int DD2 = 512;   // 2*H
constexpr int TC  = 128;   // timestep chunk
constexpr int NCH = TT / TC;
constexpr int SLAB = 16 * G3;  // f16 per (dir,step,16-row slice) px slab = 24576 B

constexpr float SR = -1.44269504f;  // -log2(e): sigmoid via exp2
constexpr float SN = 2.88539009f;   // 2*log2(e): tanh via exp2

#define MF(a, b, c) __builtin_amdgcn_mfma_f32_16x16x32_f16(a, b, c, 0, 0, 0)

// ---------------- weight fp32 -> fp16 ----------------
__global__ void convw(const float* __restrict__ a, const float* __restrict__ b,
                      const float* __restrict__ c, const float* __restrict__ d,
                      f16* __restrict__ oa, f16* __restrict__ ob,
                      f16* __restrict__ oc, f16* __restrict__ od) {
  int i = blockIdx.x * blockDim.x + threadIdx.x;
  int s = gridDim.x * blockDim.x;
  for (int j = i; j < 2 * G3 * INF; j += s) oa[j] = (f16)a[j];
  for (int j = i; j < 2 * G3 * HH;  j += s) ob[j] = (f16)b[j];
  for (int j = i; j < 2 * G3 * DD2; j += s) oc[j] = (f16)c[j];
  for (int j = i; j < 2 * G3 * HH;  j += s) od[j] = (f16)d[j];
}

// ---------------- input-projection GEMM ----------------
// grid (TC, 12, 2), block 256 (4 waves, 2x2).  Writes px in consumer-lane-major
// slabs, PRE-SCALED for the recur epilogue (see header).
template <int KD, bool AF16>
__global__ __launch_bounds__(256) void px_gemm(const void* __restrict__ Ain,
                                               const f16* __restrict__ W,
                                               const float* __restrict__ bih,
                                               const float* __restrict__ bhh,
                                               f16* __restrict__ px, int c) {
  __shared__ __align__(16) f16 As[128][40];
  __shared__ __align__(16) f16 Bs[64][40];
  const int d = blockIdx.z, mt = blockIdx.x, nt = blockIdx.y;
  const int t = d ? (TT - 1 - (c * TC + mt)) : (c * TC + mt);
  const int tid = threadIdx.x, lane = tid & 63, w = tid >> 6;
  const int wm = w >> 1, wn = w & 1;
  const f16* Wd = W + (size_t)d * G3 * KD;
  f32x4 acc[4][2];
  const f32x4 zz = {0.f, 0.f, 0.f, 0.f};
#pragma unroll
  for (int mi = 0; mi < 4; ++mi)
#pragma unroll
    for (int ni = 0; ni < 2; ++ni) acc[mi][ni] = zz;

  for (int kb = 0; kb < KD / 32; ++kb) {
    const int k0 = kb * 32;
    if constexpr (AF16) {       // y0 [T][B][512] f16
      const f16* A = (const f16*)Ain;
#pragma unroll
      for (int p = 0; p < 2; ++p) {
        int idx = p * 256 + tid;
        int row = idx >> 2, kc = idx & 3;
        f16x8 v = *(const f16x8*)(A + ((size_t)t * BB + row) * DD2 + k0 + kc * 8);
        *(f16x8*)&As[row][kc * 8] = v;
      }
    } else {                    // data [B][T][128] f32 -> f16
      const float* A = (const float*)Ain;
#pragma unroll
      for (int p = 0; p < 4; ++p) {
        int idx = p * 256 + tid;
        int row = idx >> 3, kc = idx & 7;
        const float* srcp = A + (size_t)row * (TT * INF) + t * INF + k0 + kc * 4;
        float4 v = *(const float4*)srcp;
        f16x4 h4;
        h4[0] = (f16)v.x; h4[1] = (f16)v.y; h4[2] = (f16)v.z; h4[3] = (f16)v.w;
        *(f16x4*)&As[row][kc * 4] = h4;
      }
    }
    {
      int row = tid >> 2, kc = tid & 3;
      f16x8 v = *(const f16x8*)(Wd + (size_t)(nt * 64 + row) * KD + k0 + kc * 8);
      *(f16x8*)&Bs[row][kc * 8] = v;
    }
    __syncthreads();
#pragma unroll
    for (int mi = 0; mi < 4; ++mi) {
      f16x8 av = *(const f16x8*)&As[wm * 64 + mi * 16 + (lane & 15)][(lane >> 4) * 8];
#pragma unroll
      for (int ni = 0; ni < 2; ++ni) {
        f16x8 bv = *(const f16x8*)&Bs[wn * 32 + ni * 16 + (lane & 15)][(lane >> 4) * 8];
        acc[mi][ni] = __builtin_amdgcn_mfma_f32_16x16x32_f16(av, bv, acc[mi][ni], 0, 0, 0);
      }
    }
    __syncthreads();
  }

  float bias[2], scale[2];
#pragma unroll
  for (int ni = 0; ni < 2; ++ni) {
    int col = nt * 64 + wn * 32 + ni * 16 + (lane & 15);
    if (col < 2 * HH) { scale[ni] = SR; bias[ni] = bih[d * G3 + col] + bhh[d * G3 + col]; }
    else              { scale[ni] = SN; bias[ni] = bih[d * G3 + col]; }
  }
#pragma unroll
  for (int mi = 0; mi < 4; ++mi)
#pragma unroll
    for (int ni = 0; ni < 2; ++ni)
#pragma unroll
      for (int r = 0; r < 4; ++r) {
        int brow = wm * 64 + mi * 16 + (lane >> 4) * 4 + r;
        int col = nt * 64 + wn * 32 + ni * 16 + (lane & 15);
        int g = col >> 8, ch = col & 255;
        size_t slab = (size_t)((d * TC + mt) * 8 + (brow >> 4)) * SLAB;
        int off = ((ch >> 5) * 64 + ((brow & 15) >> 2) * 16 + (ch & 15)) * 24 +
                  (g * 2 + ((ch >> 4) & 1)) * 4 + (brow & 3);
        px[slab + off] = (f16)(scale[ni] * (acc[mi][ni][r] + bias[ni]));
      }
}

// ---------------- persistent recurrent kernel ----------------
// grid 16 blocks: d = blk>>3, batch slice = (blk&7)*16.  8 waves; wave w owns
// hidden cols [w*32, w*32+32) for all 3 gates.  w_hh resident (unified VGPR/AGPR file).
template <int LAYER>
__global__ __launch_bounds__(512, 2) void recur(const f16* __restrict__ px,
                                                const f16* __restrict__ whh,
                                                const float* __restrict__ bhh,
                                                float* __restrict__ hstate,
                                                f16* __restrict__ y0, int c) {
  __shared__ __align__(16) f16 hbuf[2 * 16 * 256];  // double-buffered h, bits4-5 swizzle
  char* HB = (char*)hbuf;
  const int d = blockIdx.x >> 3, b0 = (blockIdx.x & 7) * 16;
  const int tid = threadIdx.x, lane = tid & 63, w = tid >> 6;
  const int cl = lane & 15, hi = lane >> 4, r0 = hi * 4;

  const f16* wd = whh + (size_t)d * G3 * HH;
  f16x8 bf[3][2][8];  // [gate][coltile][ktile] — resident weights
#pragma unroll
  for (int g = 0; g < 3; ++g)
#pragma unroll
    for (int ct = 0; ct < 2; ++ct)
#pragma unroll
      for (int kt = 0; kt < 8; ++kt) {
        int col = g * HH + w * 32 + ct * 16 + cl;
        int k = kt * 32 + hi * 8;
        bf[g][ct][kt] = *(const f16x8*)(wd + (size_t)col * HH + k);
      }
  float bn[2];  // b_hh n-gate (folded into acc init; r,z folded into px)
#pragma unroll
  for (int ct = 0; ct < 2; ++ct)
    bn[ct] = bhh[d * G3 + 2 * HH + w * 32 + ct * 16 + cl];

  // persistent address bases (zero per-step VALU):
  //   read:  A-frag (row=cl, k-bytes kt*64+hi*16) at  vb + kt*64 (+8192 odd steps)
  //   write: h[row=r0+r][col=w*32+ct*16+cl]       at  wb(r&1) + r*512 + (ct^((r>>1)&1))*32 (+buf)
  const unsigned vb = cl * 512 + ((hi * 16) ^ ((cl & 3) << 4));
  const unsigned wbase = hi * 4 * 512 + w * 64 + (cl & 7) * 2 + (((cl >> 3) & 1) << 4);
  const unsigned wb0 = wbase, wb1 = wbase ^ 16;

  float hreg[2][4];  // fp32 h master state: [coltile][row]
  if (c == 0) {
#pragma unroll
    for (int ct = 0; ct < 2; ++ct)
#pragma unroll
      for (int r = 0; r < 4; ++r) hreg[ct][r] = 0.f;
    for (int j = tid; j < 16 * 256; j += 512) hbuf[j] = (f16)0.f;
  } else {
#pragma unroll
    for (int ct = 0; ct < 2; ++ct)
#pragma unroll
      for (int r = 0; r < 4; ++r) {
        float v = hstate[((size_t)d * BB + b0 + r0 + r) * HH + w * 32 + ct * 16 + cl];
        hreg[ct][r] = v;
        unsigned wa = ((r & 1) ? wb1 : wb0) + r * 512 + ((ct ^ ((r >> 1) & 1)) << 5);
        *(f16*)(HB + wa) = (f16)v;
      }
  }

  // per-step px pointer (consumer-lane-major: this thread's 24 f16 contiguous)
  const f16* pp = px + (size_t)(d * TC * 8 + (b0 >> 4)) * SLAB + (size_t)(w * 64 + lane) * 24;
  // per-thread y0 pointer walks physical time
  f16* ypt = nullptr;
  ptrdiff_t ystep = 0;
  if constexpr (LAYER == 0) {
    int t0 = d ? (TT - 1 - c * TC) : (c * TC);
    ypt = y0 + ((size_t)t0 * BB + b0 + hi * 4) * DD2 + d * HH + w * 32 + cl;
    ystep = d ? -(ptrdiff_t)(BB * DD2) : (ptrdiff_t)(BB * DD2);
  }

  for (int ib = 0; ib < TC; ib += 2) {
#pragma unroll
    for (int s = 0; s < 2; ++s) {
      const int roB = s ? 8192 : 0;   // buffer read this step
      const int wrB = s ? 0 : 8192;   // buffer written this step
      // one barrier per step; lgkm-only drain (no vmcnt stall on y0 stores)
      asm volatile("s_waitcnt lgkmcnt(0)" ::: "memory");
      __builtin_amdgcn_sched_barrier(0);
      __builtin_amdgcn_s_barrier();
      __builtin_amdgcn_sched_barrier(0);

      // px loads for this step: consumed in epilogue, hidden under MFMA phase
      f16x8 p0 = *(const f16x8*)(pp);
      f16x8 p1 = *(const f16x8*)(pp + 8);
      f16x8 p2 = *(const f16x8*)(pp + 16);
      pp += 8 * SLAB;

      f32x4 acc[3][2];
      const f32x4 zz = {0.f, 0.f, 0.f, 0.f};
#pragma unroll
      for (int ct = 0; ct < 2; ++ct) {
        acc[0][ct] = zz;
        acc[1][ct] = zz;
        acc[2][ct] = (f32x4){bn[ct], bn[ct], bn[ct], bn[ct]};
      }

      // MFMA phase, 3-deep rotating A-frag prefetch
      f16x8 a0 = *(const f16x8*)(HB + vb + roB + 0 * 64);
      f16x8 a1 = *(const f16x8*)(HB + vb + roB + 1 * 64);
      f16x8 a2 = *(const f16x8*)(HB + vb + roB + 2 * 64);
#pragma unroll
      for (int kt = 0; kt < 8; ++kt) {
        f16x8 an;
        if (kt < 5) an = *(const f16x8*)(HB + vb + roB + (kt + 3) * 64);
        acc[0][0] = MF(a0, bf[0][0][kt], acc[0][0]);
        acc[0][1] = MF(a0, bf[0][1][kt], acc[0][1]);
        acc[1][0] = MF(a0, bf[1][0][kt], acc[1][0]);
        acc[1][1] = MF(a0, bf[1][1][kt], acc[1][1]);
        acc[2][0] = MF(a0, bf[2][0][kt], acc[2][0]);
        acc[2][1] = MF(a0, bf[2][1][kt], acc[2][1]);
        a0 = a1; a1 = a2; a2 = an;
      }

      // epilogue: gates + h update; writes go to the OTHER buffer (no 2nd barrier)
#pragma unroll
      for (int ct = 0; ct < 2; ++ct)
#pragma unroll
        for (int r = 0; r < 4; ++r) {
          float pr = (float)p0[ct * 4 + r];
          float pz = (float)p1[ct * 4 + r];
          float pn = (float)p2[ct * 4 + r];
          float er = __builtin_amdgcn_exp2f(__builtin_fmaf(acc[0][ct][r], SR, pr));
          float rg = __builtin_amdgcn_rcpf(1.f + er);
          float ez = __builtin_amdgcn_exp2f(__builtin_fmaf(acc[1][ct][r], SR, pz));
          float zg = __builtin_amdgcn_rcpf(1.f + ez);
          float en = __builtin_amdgcn_exp2f(__builtin_fmaf(rg * SN, acc[2][ct][r], pn));
          float tn = __builtin_amdgcn_rcpf(1.f + en);
          float ng = __builtin_fmaf(-2.f, tn, 1.f);
          float hv = __builtin_fmaf(zg, hreg[ct][r] - ng, ng);
          hreg[ct][r] = hv;
          unsigned wa = ((r & 1) ? wb1 : wb0) + r * 512 + ((ct ^ ((r >> 1) & 1)) << 5) + wrB;
          *(f16*)(HB + wa) = (f16)hv;
          if constexpr (LAYER == 0) ypt[r * DD2 + ct * 16] = (f16)hv;
        }
      if constexpr (LAYER == 0) ypt += ystep;
    }
  }
#pragma unroll
  for (int ct = 0; ct < 2; ++ct)
#pragma unroll
    for (int r = 0; r < 4; ++r)
      hstate[((size_t)d * BB + b0 + r0 + r) * HH + w * 32 + ct * 16 + cl] = hreg[ct][r];
}

// ---------------- output head ----------------
__global__ void head(const float* __restrict__ hstate, const float* __restrict__ wout,
                     const float* __restrict__ bout, float* __restrict__ out) {
  int g = blockIdx.x * blockDim.x + threadIdx.x;  // 0..511
  if (g >= BB * 4) return;
  int b = g >> 2, o = g & 3;
  float s = bout[o];
  for (int jj = 0; jj < DD2; ++jj) {
    int dd = jj >> 8, j = jj & 255;
    s += hstate[((size_t)dd * BB + b) * HH + j] * wout[o * DD2 + jj];
  }
  out[g] = s;
}

extern "C" void kernel_launch(void* const* d_in, const int* in_sizes, int n_in,
                              void* d_out, int out_size, void* d_ws, size_t ws_size,
                              hipStream_t stream) {
  const float* data = (const float*)d_in[0];
  const float* wih0 = (const float*)d_in[1];
  const float* whh0 = (const float*)d_in[2];
  const float* bih0 = (const float*)d_in[3];
  const float* bhh0 = (const float*)d_in[4];
  const float* wih1 = (const float*)d_in[5];
  const float* whh1 = (const float*)d_in[6];
  const float* bih1 = (const float*)d_in[7];
  const float* bhh1 = (const float*)d_in[8];
  const float* wout = (const float*)d_in[9];
  const float* bout = (const float*)d_in[10];

  char* ws = (char*)d_ws;
  f16*   f_wih0 = (f16*)(ws + 0);          //  393216 B
  f16*   f_whh0 = (f16*)(ws + 393216);     //  786432 B
  f16*   f_wih1 = (f16*)(ws + 1179648);    // 1572864 B
  f16*   f_whh1 = (f16*)(ws + 2752512);    //  786432 B
  float* hstate = (float*)(ws + 3538944);  //  262144 B
  f16*   y0     = (f16*)(ws + 4194304);    // 134217728 B  [T][B][512]
  f16*   px     = (f16*)(ws + 138412032);  //  50331648 B  [2][TC][8 slabs][16*768]
  // total 188743680 B

  convw<<<512, 256, 0, stream>>>(wih0, whh0, wih1, whh1, f_wih0, f_whh0, f_wih1, f_whh1);

  dim3 gg(TC, 12, 2);
  for (int c = 0; c < NCH; ++c) {
    px_gemm<INF, false><<<gg, 256, 0, stream>>>(data, f_wih0, bih0, bhh0, px, c);
    recur<0><<<16, 512, 0, stream>>>(px, f_whh0, bhh0, hstate, y0, c);
  }
  for (int c = 0; c < NCH; ++c) {
    px_gemm<DD2, true><<<gg, 256, 0, stream>>>(y0, f_wih1, bih1, bhh1, px, c);
    recur<1><<<16, 512, 0, stream>>>(px, f_whh1, bhh1, hstate, nullptr, c);
  }
  head<<<4, 128, 0, stream>>>(hstate, wout, bout, (float*)d_out);
}

// Round 5
// 4226.226 us; speedup vs baseline: 2.6417x; 1.0299x over previous
//
#include <hip/hip_runtime.h>

// GRU_8667244003631 — 2-layer bidirectional GRU, B=128 T=1024 IN=128 H=256 OUT=4.
// Round 5:
//   * FUSED dispatches: blocks 0-15 run recur chunk c; blocks 16+ run the px GEMM for
//     chunk c+1 into a 2-slot ring (TC=64 so ws stays 188.7 MB). px time fully hidden.
//   * recur LDS: full (row&7)<<4 XOR swizzle, conflict-free (8-slot spread), with
//     zero per-step address VALU: reads use addr = rb ^ (kt<<6) (one v_xor each),
//     writes use 4 precomputed bases + {0,32} immediates.
//   * recur math unchanged from round 4 (pre-scaled px, exp2/rcp gates, bn in acc init).

typedef _Float16 f16;
typedef __attribute__((ext_vector_type(8))) _Float16 f16x8;
typedef __attribute__((ext_vector_type(4))) _Float16 f16x4;
typedef __attribute__((ext_vector_type(4))) float f32x4;

constexpr int BB  = 128;
constexpr int TT  = 1024;
constexpr int INF = 128;
constexpr int HH  = 256;
constexpr int G3  = 768;
constexpr int DD2 = 512;
constexpr int TC  = 64;          // timestep chunk
constexpr int NCH = TT / TC;     // 16
constexpr int SLAB = 16 * G3;    // f16 elems per (step, 16-row slice) px slab
constexpr int PXCHUNK = 2 * TC * 8 * SLAB;  // f16 elems per px ring slot
constexpr int NPXB = TC * 6 * 2; // 768 px blocks per chunk (64 mt x 6 pairs x 2 dirs)

constexpr float SR = -1.44269504f;  // -log2(e)
constexpr float SN = 2.88539009f;   // 2*log2(e)

#define MF(a, b, c) __builtin_amdgcn_mfma_f32_16x16x32_f16(a, b, c, 0, 0, 0)

__global__ void convw(const float* __restrict__ a, const float* __restrict__ b,
                      const float* __restrict__ c, const float* __restrict__ d,
                      f16* __restrict__ oa, f16* __restrict__ ob,
                      f16* __restrict__ oc, f16* __restrict__ od) {
  int i = blockIdx.x * blockDim.x + threadIdx.x;
  int s = gridDim.x * blockDim.x;
  for (int j = i; j < 2 * G3 * INF; j += s) oa[j] = (f16)a[j];
  for (int j = i; j < 2 * G3 * HH;  j += s) ob[j] = (f16)b[j];
  for (int j = i; j < 2 * G3 * DD2; j += s) oc[j] = (f16)c[j];
  for (int j = i; j < 2 * G3 * HH;  j += s) od[j] = (f16)d[j];
}

// ---------------- fused kernel: recur role (blocks 0..15) + px role (blocks 16..) ----
// LAYER: recur layer. PXKD/PXF16: px GEMM K-dim / A dtype. HASRECUR=false -> px-only.
template <int LAYER, int PXKD, bool PXF16, bool HASRECUR>
__global__ __launch_bounds__(512, 2) void fused(
    const f16* __restrict__ pxin, f16* __restrict__ pxout,
    const f16* __restrict__ whh, const float* __restrict__ bhh,
    float* __restrict__ hstate, f16* __restrict__ y0,
    const void* __restrict__ pxA, const f16* __restrict__ wih,
    const float* __restrict__ bih, const float* __restrict__ bhhpx,
    int c, int cpx) {
  __shared__ __align__(16) char smem[20480];
  const int tid = threadIdx.x, lane = tid & 63, w = tid >> 6;
  const int cl = lane & 15, hi = lane >> 4;

  if (HASRECUR && blockIdx.x < 16) {
    // ================= recur role =================
    char* HB = smem;                       // h double buffer [2][16 rows][512 B], swizzled
    const int bid = blockIdx.x;
    const int d = bid >> 3, b0 = (bid & 7) * 16, r0 = hi * 4;

    const f16* wd = whh + (size_t)d * G3 * HH;
    f16x8 bf[3][2][8];
#pragma unroll
    for (int g = 0; g < 3; ++g)
#pragma unroll
      for (int ct = 0; ct < 2; ++ct)
#pragma unroll
        for (int kt = 0; kt < 8; ++kt) {
          int col = g * HH + w * 32 + ct * 16 + cl;
          int k = kt * 32 + hi * 8;
          bf[g][ct][kt] = *(const f16x8*)(wd + (size_t)col * HH + k);
        }
    float bn[2];
#pragma unroll
    for (int ct = 0; ct < 2; ++ct)
      bn[ct] = bhh[d * G3 + 2 * HH + w * 32 + ct * 16 + cl];

    // read base: element (row=cl, k) lives at cl*512 + ((k*2) ^ ((cl&7)<<4)).
    // A-frag (kt,hi) chunk base = rb ^ (kt<<6), rb = cl*512 + (hi*16 ^ ((cl&3)<<4)) + ((cl&4)<<4)
    const unsigned rb = (unsigned)cl * 512 + (((unsigned)hi * 16) ^ ((unsigned)(cl & 3) << 4)) +
                        ((unsigned)(cl & 4) << 4);
    // write bases per r (ct=0/1 via +{0,32} immediates)
    unsigned wbase[4];
#pragma unroll
    for (int r = 0; r < 4; ++r)
      wbase[r] = (unsigned)(hi * 4 + r) * 512 +
                 ((((unsigned)w * 64) + (unsigned)cl * 2) ^
                  ((((unsigned)hi & 1) << 6) | ((unsigned)r << 4))) +
                 ((r & 2) ? -32 : 0);

    float hreg[2][4];
    if (c == 0) {
#pragma unroll
      for (int ct = 0; ct < 2; ++ct)
#pragma unroll
        for (int r = 0; r < 4; ++r) hreg[ct][r] = 0.f;
      for (int j = tid; j < 16 * 256; j += 512) ((f16*)HB)[j] = (f16)0.f;
    } else {
#pragma unroll
      for (int ct = 0; ct < 2; ++ct)
#pragma unroll
        for (int r = 0; r < 4; ++r) {
          int row = r0 + r, col = w * 32 + ct * 16 + cl;
          float v = hstate[((size_t)d * BB + b0 + row) * HH + col];
          hreg[ct][r] = v;
          unsigned wa = (unsigned)row * 512 + (((unsigned)col * 2) ^ ((unsigned)(row & 7) << 4));
          *(f16*)(HB + wa) = (f16)v;
        }
    }

    const f16* pp = pxin + (size_t)(d * TC * 8 + (bid & 7)) * SLAB + (size_t)(w * 64 + lane) * 24;
    f16* ypt = nullptr;
    ptrdiff_t ystep = 0;
    if constexpr (LAYER == 0) {
      int t0 = d ? (TT - 1 - c * TC) : (c * TC);
      ypt = y0 + ((size_t)t0 * BB + b0 + hi * 4) * DD2 + d * HH + w * 32 + cl;
      ystep = d ? -(ptrdiff_t)(BB * DD2) : (ptrdiff_t)(BB * DD2);
    }

    for (int ib = 0; ib < TC; ib += 2) {
#pragma unroll
      for (int s = 0; s < 2; ++s) {
        const int roB = s ? 8192 : 0;   // buffer read this step
        const int wrB = s ? 0 : 8192;   // buffer written this step
        asm volatile("s_waitcnt lgkmcnt(0)" ::: "memory");
        __builtin_amdgcn_sched_barrier(0);
        __builtin_amdgcn_s_barrier();
        __builtin_amdgcn_sched_barrier(0);

        f16x8 p0 = *(const f16x8*)(pp);
        f16x8 p1 = *(const f16x8*)(pp + 8);
        f16x8 p2 = *(const f16x8*)(pp + 16);
        pp += 8 * SLAB;

        f32x4 acc[3][2];
        const f32x4 zz = {0.f, 0.f, 0.f, 0.f};
#pragma unroll
        for (int ct = 0; ct < 2; ++ct) {
          acc[0][ct] = zz;
          acc[1][ct] = zz;
          acc[2][ct] = (f32x4){bn[ct], bn[ct], bn[ct], bn[ct]};
        }

        f16x8 a0 = *(const f16x8*)(HB + ((rb ^ (0u << 6)) + roB));
        f16x8 a1 = *(const f16x8*)(HB + ((rb ^ (1u << 6)) + roB));
        f16x8 a2 = *(const f16x8*)(HB + ((rb ^ (2u << 6)) + roB));
#pragma unroll
        for (int kt = 0; kt < 8; ++kt) {
          f16x8 an;
          if (kt < 5) an = *(const f16x8*)(HB + ((rb ^ ((unsigned)(kt + 3) << 6)) + roB));
          acc[0][0] = MF(a0, bf[0][0][kt], acc[0][0]);
          acc[0][1] = MF(a0, bf[0][1][kt], acc[0][1]);
          acc[1][0] = MF(a0, bf[1][0][kt], acc[1][0]);
          acc[1][1] = MF(a0, bf[1][1][kt], acc[1][1]);
          acc[2][0] = MF(a0, bf[2][0][kt], acc[2][0]);
          acc[2][1] = MF(a0, bf[2][1][kt], acc[2][1]);
          a0 = a1; a1 = a2; a2 = an;
        }

#pragma unroll
        for (int ct = 0; ct < 2; ++ct)
#pragma unroll
          for (int r = 0; r < 4; ++r) {
            float pr = (float)p0[ct * 4 + r];
            float pz = (float)p1[ct * 4 + r];
            float pn = (float)p2[ct * 4 + r];
            float er = __builtin_amdgcn_exp2f(__builtin_fmaf(acc[0][ct][r], SR, pr));
            float rg = __builtin_amdgcn_rcpf(1.f + er);
            float ez = __builtin_amdgcn_exp2f(__builtin_fmaf(acc[1][ct][r], SR, pz));
            float zg = __builtin_amdgcn_rcpf(1.f + ez);
            float en = __builtin_amdgcn_exp2f(__builtin_fmaf(rg * SN, acc[2][ct][r], pn));
            float tn = __builtin_amdgcn_rcpf(1.f + en);
            float ng = __builtin_fmaf(-2.f, tn, 1.f);
            float hv = __builtin_fmaf(zg, hreg[ct][r] - ng, ng);
            hreg[ct][r] = hv;
            unsigned wa = wbase[r] + (ct ? ((r & 2) ? 0 : 32) : ((r & 2) ? 32 : 0)) + wrB;
            *(f16*)(HB + wa) = (f16)hv;
            if constexpr (LAYER == 0) ypt[r * DD2 + ct * 16] = (f16)hv;
          }
        if constexpr (LAYER == 0) ypt += ystep;
      }
    }
#pragma unroll
    for (int ct = 0; ct < 2; ++ct)
#pragma unroll
      for (int r = 0; r < 4; ++r)
        hstate[((size_t)d * BB + b0 + r0 + r) * HH + w * 32 + ct * 16 + cl] = hreg[ct][r];
    return;
  }

  // ================= px role =================
  {
    const int pb = HASRECUR ? (int)blockIdx.x - 16 : (int)blockIdx.x;
    const int mt = pb & (TC - 1), rest = pb >> 6;
    const int pair = rest % 6, d = rest / 6;
    const int t = d ? (TT - 1 - (cpx * TC + mt)) : (cpx * TC + mt);
    f16 (*As)[40] = (f16(*)[40])smem;
    f16* Bsf = (f16*)(smem + 10240);   // [2][64][40]
    const int wn = w & 1, wm = (w >> 1) & 1, ntsub = w >> 2;
    const int nt = pair * 2 + ntsub;
    const f16* Wd = wih + (size_t)d * G3 * PXKD;

    f32x4 acc[4][2];
    const f32x4 zz = {0.f, 0.f, 0.f, 0.f};
#pragma unroll
    for (int mi = 0; mi < 4; ++mi)
#pragma unroll
      for (int ni = 0; ni < 2; ++ni) acc[mi][ni] = zz;

    for (int kb = 0; kb < PXKD / 32; ++kb) {
      const int k0 = kb * 32;
      {
        int row = tid >> 2, kc = tid & 3;
        if constexpr (PXF16) {
          const f16* A = (const f16*)pxA;
          f16x8 v = *(const f16x8*)(A + ((size_t)t * BB + row) * DD2 + k0 + kc * 8);
          *(f16x8*)&As[row][kc * 8] = v;
        } else {
          const float* A = (const float*)pxA;
#pragma unroll
          for (int p = 0; p < 2; ++p) {
            float4 v = *(const float4*)(A + (size_t)row * (TT * INF) + t * INF + k0 + kc * 8 + p * 4);
            f16x4 h4;
            h4[0] = (f16)v.x; h4[1] = (f16)v.y; h4[2] = (f16)v.z; h4[3] = (f16)v.w;
            *(f16x4*)&As[row][kc * 8 + p * 4] = h4;
          }
        }
        int nts = tid >> 8, t2 = tid & 255;
        int brow = t2 >> 2, bkc = t2 & 3;
        f16x8 v = *(const f16x8*)(Wd + (size_t)((pair * 2 + nts) * 64 + brow) * PXKD + k0 + bkc * 8);
        *(f16x8*)&Bsf[(nts * 64 + brow) * 40 + bkc * 8] = v;
      }
      __syncthreads();
#pragma unroll
      for (int mi = 0; mi < 4; ++mi) {
        f16x8 av = *(const f16x8*)&As[wm * 64 + mi * 16 + cl][hi * 8];
#pragma unroll
        for (int ni = 0; ni < 2; ++ni) {
          f16x8 bv = *(const f16x8*)&Bsf[(ntsub * 64 + wn * 32 + ni * 16 + cl) * 40 + hi * 8];
          acc[mi][ni] = __builtin_amdgcn_mfma_f32_16x16x32_f16(av, bv, acc[mi][ni], 0, 0, 0);
        }
      }
      __syncthreads();
    }

    float bias[2], scale[2];
#pragma unroll
    for (int ni = 0; ni < 2; ++ni) {
      int col = nt * 64 + wn * 32 + ni * 16 + cl;
      if (col < 2 * HH) { scale[ni] = SR; bias[ni] = bih[d * G3 + col] + bhhpx[d * G3 + col]; }
      else              { scale[ni] = SN; bias[ni] = bih[d * G3 + col]; }
    }
#pragma unroll
    for (int mi = 0; mi < 4; ++mi)
#pragma unroll
      for (int ni = 0; ni < 2; ++ni)
#pragma unroll
        for (int r = 0; r < 4; ++r) {
          int brow = wm * 64 + mi * 16 + hi * 4 + r;
          int col = nt * 64 + wn * 32 + ni * 16 + cl;
          int g = col >> 8, ch = col & 255;
          size_t slab = (size_t)((d * TC + mt) * 8 + (brow >> 4)) * SLAB;
          int off = ((ch >> 5) * 64 + ((brow & 15) >> 2) * 16 + (ch & 15)) * 24 +
                    (g * 2 + ((ch >> 4) & 1)) * 4 + (brow & 3);
          pxout[slab + off] = (f16)(scale[ni] * (acc[mi][ni][r] + bias[ni]));
        }
  }
}

__global__ void head(const float* __restrict__ hstate, const float* __restrict__ wout,
                     const float* __restrict__ bout, float* __restrict__ out) {
  int g = blockIdx.x * blockDim.x + threadIdx.x;
  if (g >= BB * 4) return;
  int b = g >> 2, o = g & 3;
  float s = bout[o];
  for (int jj = 0; jj < DD2; ++jj) {
    int dd = jj >> 8, j = jj & 255;
    s += hstate[((size_t)dd * BB + b) * HH + j] * wout[o * DD2 + jj];
  }
  out[g] = s;
}

extern "C" void kernel_launch(void* const* d_in, const int* in_sizes, int n_in,
                              void* d_out, int out_size, void* d_ws, size_t ws_size,
                              hipStream_t stream) {
  const float* data = (const float*)d_in[0];
  const float* wih0 = (const float*)d_in[1];
  const float* whh0 = (const float*)d_in[2];
  const float* bih0 = (const float*)d_in[3];
  const float* bhh0 = (const float*)d_in[4];
  const float* wih1 = (const float*)d_in[5];
  const float* whh1 = (const float*)d_in[6];
  const float* bih1 = (const float*)d_in[7];
  const float* bhh1 = (const float*)d_in[8];
  const float* wout = (const float*)d_in[9];
  const float* bout = (const float*)d_in[10];

  char* ws = (char*)d_ws;
  f16*   f_wih0 = (f16*)(ws + 0);
  f16*   f_whh0 = (f16*)(ws + 393216);
  f16*   f_wih1 = (f16*)(ws + 1179648);
  f16*   f_whh1 = (f16*)(ws + 2752512);
  float* hstate = (float*)(ws + 3538944);
  f16*   y0     = (f16*)(ws + 4194304);     // 134217728 B  [T][B][512]
  f16*   pxr    = (f16*)(ws + 138412032);   // 2 ring slots x 25165824 B
  // total 188743680 B

  f16* slot[2] = {pxr, pxr + PXCHUNK};

  convw<<<512, 256, 0, stream>>>(wih0, whh0, wih1, whh1, f_wih0, f_whh0, f_wih1, f_whh1);

  // ---- layer 0 ----
  fused<0, INF, false, false><<<NPXB, 512, 0, stream>>>(
      nullptr, slot[0], f_whh0, bhh0, hstate, y0, data, f_wih0, bih0, bhh0, 0, 0);
  for (int c = 0; c < NCH; ++c) {
    int npx = (c + 1 < NCH) ? NPXB : 0;
    fused<0, INF, false, true><<<16 + npx, 512, 0, stream>>>(
        slot[c & 1], slot[(c + 1) & 1], f_whh0, bhh0, hstate, y0,
        data, f_wih0, bih0, bhh0, c, c + 1);
  }
  // ---- layer 1 ----
  fused<1, DD2, true, false><<<NPXB, 512, 0, stream>>>(
      nullptr, slot[0], f_whh1, bhh1, hstate, nullptr, y0, f_wih1, bih1, bhh1, 0, 0);
  for (int c = 0; c < NCH; ++c) {
    int npx = (c + 1 < NCH) ? NPXB : 0;
    fused<1, DD2, true, true><<<16 + npx, 512, 0, stream>>>(
        slot[c & 1], slot[(c + 1) & 1], f_whh1, bhh1, hstate, nullptr,
        y0, f_wih1, bih1, bhh1, c, c + 1);
  }
  head<<<4, 128, 0, stream>>>(hstate, wout, bout, (float*)d_out);
}

// Round 6
// 4211.599 us; speedup vs baseline: 2.6508x; 1.0035x over previous
//
#include <hip/hip_runtime.h>

// GRU_8667244003631 — 2-layer bidirectional GRU, B=128 T=1024 IN=128 H=256 OUT=4.
// Round 6:
//   * CU isolation: fused kernel takes 86016 B static LDS -> 1 block/CU everywhere,
//     so px blocks can never co-reside with a recur block (round-5: sharing a CU cost
//     recur +54%/step). px-only prologs keep 40960 B (2 blocks/CU).
//   * px role: KSTEP=64 staging (As/Bs [128][72] f16, 2 MFMA k-subtiles per stage)
//     halves the latency-bound stage count so px at 1 blk/CU stays hidden under recur.
//   * recur internals unchanged from round 5 (XOR-swizzled zero-VALU LDS addressing,
//     pre-scaled px, exp2/rcp gates).

typedef _Float16 f16;
typedef __attribute__((ext_vector_type(8))) _Float16 f16x8;
typedef __attribute__((ext_vector_type(4))) _Float16 f16x4;
typedef __attribute__((ext_vector_type(4))) float f32x4;

constexpr int BB  = 128;
constexpr int TT  = 1024;
constexpr int INF = 128;
constexpr int HH  = 256;
constexpr int G3  = 768;
constexpr int DD2 = 512;
constexpr int TC  = 64;          // timestep chunk
constexpr int NCH = TT / TC;     // 16
constexpr int SLAB = 16 * G3;    // f16 elems per (step, 16-row slice) px slab
constexpr int PXCHUNK = 2 * TC * 8 * SLAB;  // f16 elems per px ring slot
constexpr int NPXB = TC * 6 * 2; // 768 px blocks per chunk

constexpr float SR = -1.44269504f;  // -log2(e)
constexpr float SN = 2.88539009f;   // 2*log2(e)

#define MF(a, b, c) __builtin_amdgcn_mfma_f32_16x16x32_f16(a, b, c, 0, 0, 0)

__global__ void convw(const float* __restrict__ a, const float* __restrict__ b,
                      const float* __restrict__ c, const float* __restrict__ d,
                      f16* __restrict__ oa, f16* __restrict__ ob,
                      f16* __restrict__ oc, f16* __restrict__ od) {
  int i = blockIdx.x * blockDim.x + threadIdx.x;
  int s = gridDim.x * blockDim.x;
  for (int j = i; j < 2 * G3 * INF; j += s) oa[j] = (f16)a[j];
  for (int j = i; j < 2 * G3 * HH;  j += s) ob[j] = (f16)b[j];
  for (int j = i; j < 2 * G3 * DD2; j += s) oc[j] = (f16)c[j];
  for (int j = i; j < 2 * G3 * HH;  j += s) od[j] = (f16)d[j];
}

// ---------------- fused kernel: recur role (blocks 0..15) + px role (blocks 16..) ----
template <int LAYER, int PXKD, bool PXF16, bool HASRECUR, int SMEMSZ>
__global__ __launch_bounds__(512, 2) void fused(
    const f16* __restrict__ pxin, f16* __restrict__ pxout,
    const f16* __restrict__ whh, const float* __restrict__ bhh,
    float* __restrict__ hstate, f16* __restrict__ y0,
    const void* __restrict__ pxA, const f16* __restrict__ wih,
    const float* __restrict__ bih, const float* __restrict__ bhhpx,
    int c, int cpx) {
  __shared__ __align__(16) char smem[SMEMSZ];
  const int tid = threadIdx.x, lane = tid & 63, w = tid >> 6;
  const int cl = lane & 15, hi = lane >> 4;

  if (HASRECUR && blockIdx.x < 16) {
    // ================= recur role =================
    char* HB = smem;                       // h double buffer [2][16 rows][512 B], swizzled
    const int bid = blockIdx.x;
    const int d = bid >> 3, b0 = (bid & 7) * 16, r0 = hi * 4;

    const f16* wd = whh + (size_t)d * G3 * HH;
    f16x8 bf[3][2][8];
#pragma unroll
    for (int g = 0; g < 3; ++g)
#pragma unroll
      for (int ct = 0; ct < 2; ++ct)
#pragma unroll
        for (int kt = 0; kt < 8; ++kt) {
          int col = g * HH + w * 32 + ct * 16 + cl;
          int k = kt * 32 + hi * 8;
          bf[g][ct][kt] = *(const f16x8*)(wd + (size_t)col * HH + k);
        }
    float bn[2];
#pragma unroll
    for (int ct = 0; ct < 2; ++ct)
      bn[ct] = bhh[d * G3 + 2 * HH + w * 32 + ct * 16 + cl];

    const unsigned rb = (unsigned)cl * 512 + (((unsigned)hi * 16) ^ ((unsigned)(cl & 3) << 4)) +
                        ((unsigned)(cl & 4) << 4);
    unsigned wbase[4];
#pragma unroll
    for (int r = 0; r < 4; ++r)
      wbase[r] = (unsigned)(hi * 4 + r) * 512 +
                 ((((unsigned)w * 64) + (unsigned)cl * 2) ^
                  ((((unsigned)hi & 1) << 6) | ((unsigned)r << 4))) +
                 ((r & 2) ? -32 : 0);

    float hreg[2][4];
    if (c == 0) {
#pragma unroll
      for (int ct = 0; ct < 2; ++ct)
#pragma unroll
        for (int r = 0; r < 4; ++r) hreg[ct][r] = 0.f;
      for (int j = tid; j < 16 * 256; j += 512) ((f16*)HB)[j] = (f16)0.f;
    } else {
#pragma unroll
      for (int ct = 0; ct < 2; ++ct)
#pragma unroll
        for (int r = 0; r < 4; ++r) {
          int row = r0 + r, col = w * 32 + ct * 16 + cl;
          float v = hstate[((size_t)d * BB + b0 + row) * HH + col];
          hreg[ct][r] = v;
          unsigned wa = (unsigned)row * 512 + (((unsigned)col * 2) ^ ((unsigned)(row & 7) << 4));
          *(f16*)(HB + wa) = (f16)v;
        }
    }

    const f16* pp = pxin + (size_t)(d * TC * 8 + (bid & 7)) * SLAB + (size_t)(w * 64 + lane) * 24;
    f16* ypt = nullptr;
    ptrdiff_t ystep = 0;
    if constexpr (LAYER == 0) {
      int t0 = d ? (TT - 1 - c * TC) : (c * TC);
      ypt = y0 + ((size_t)t0 * BB + b0 + hi * 4) * DD2 + d * HH + w * 32 + cl;
      ystep = d ? -(ptrdiff_t)(BB * DD2) : (ptrdiff_t)(BB * DD2);
    }

    for (int ib = 0; ib < TC; ib += 2) {
#pragma unroll
      for (int s = 0; s < 2; ++s) {
        const int roB = s ? 8192 : 0;   // buffer read this step
        const int wrB = s ? 0 : 8192;   // buffer written this step
        asm volatile("s_waitcnt lgkmcnt(0)" ::: "memory");
        __builtin_amdgcn_sched_barrier(0);
        __builtin_amdgcn_s_barrier();
        __builtin_amdgcn_sched_barrier(0);

        f16x8 p0 = *(const f16x8*)(pp);
        f16x8 p1 = *(const f16x8*)(pp + 8);
        f16x8 p2 = *(const f16x8*)(pp + 16);
        pp += 8 * SLAB;

        f32x4 acc[3][2];
        const f32x4 zz = {0.f, 0.f, 0.f, 0.f};
#pragma unroll
        for (int ct = 0; ct < 2; ++ct) {
          acc[0][ct] = zz;
          acc[1][ct] = zz;
          acc[2][ct] = (f32x4){bn[ct], bn[ct], bn[ct], bn[ct]};
        }

        f16x8 a0 = *(const f16x8*)(HB + ((rb ^ (0u << 6)) + roB));
        f16x8 a1 = *(const f16x8*)(HB + ((rb ^ (1u << 6)) + roB));
        f16x8 a2 = *(const f16x8*)(HB + ((rb ^ (2u << 6)) + roB));
#pragma unroll
        for (int kt = 0; kt < 8; ++kt) {
          f16x8 an;
          if (kt < 5) an = *(const f16x8*)(HB + ((rb ^ ((unsigned)(kt + 3) << 6)) + roB));
          acc[0][0] = MF(a0, bf[0][0][kt], acc[0][0]);
          acc[0][1] = MF(a0, bf[0][1][kt], acc[0][1]);
          acc[1][0] = MF(a0, bf[1][0][kt], acc[1][0]);
          acc[1][1] = MF(a0, bf[1][1][kt], acc[1][1]);
          acc[2][0] = MF(a0, bf[2][0][kt], acc[2][0]);
          acc[2][1] = MF(a0, bf[2][1][kt], acc[2][1]);
          a0 = a1; a1 = a2; a2 = an;
        }

#pragma unroll
        for (int ct = 0; ct < 2; ++ct)
#pragma unroll
          for (int r = 0; r < 4; ++r) {
            float pr = (float)p0[ct * 4 + r];
            float pz = (float)p1[ct * 4 + r];
            float pn = (float)p2[ct * 4 + r];
            float er = __builtin_amdgcn_exp2f(__builtin_fmaf(acc[0][ct][r], SR, pr));
            float rg = __builtin_amdgcn_rcpf(1.f + er);
            float ez = __builtin_amdgcn_exp2f(__builtin_fmaf(acc[1][ct][r], SR, pz));
            float zg = __builtin_amdgcn_rcpf(1.f + ez);
            float en = __builtin_amdgcn_exp2f(__builtin_fmaf(rg * SN, acc[2][ct][r], pn));
            float tn = __builtin_amdgcn_rcpf(1.f + en);
            float ng = __builtin_fmaf(-2.f, tn, 1.f);
            float hv = __builtin_fmaf(zg, hreg[ct][r] - ng, ng);
            hreg[ct][r] = hv;
            unsigned wa = wbase[r] + (ct ? ((r & 2) ? 0 : 32) : ((r & 2) ? 32 : 0)) + wrB;
            *(f16*)(HB + wa) = (f16)hv;
            if constexpr (LAYER == 0) ypt[r * DD2 + ct * 16] = (f16)hv;
          }
        if constexpr (LAYER == 0) ypt += ystep;
      }
    }
#pragma unroll
    for (int ct = 0; ct < 2; ++ct)
#pragma unroll
      for (int r = 0; r < 4; ++r)
        hstate[((size_t)d * BB + b0 + r0 + r) * HH + w * 32 + ct * 16 + cl] = hreg[ct][r];
    return;
  }

  // ================= px role (KSTEP=64 staging) =================
  {
    const int pb = HASRECUR ? (int)blockIdx.x - 16 : (int)blockIdx.x;
    const int mt = pb & (TC - 1), rest = pb >> 6;
    const int pair = rest % 6, d = rest / 6;
    const int t = d ? (TT - 1 - (cpx * TC + mt)) : (cpx * TC + mt);
    f16 (*As)[72] = (f16(*)[72])smem;             // 128 x 72 f16 = 18432 B
    f16 (*Bs)[72] = (f16(*)[72])(smem + 18432);   // 128 x 72 f16 = 18432 B
    const int wn = w & 1, wm = (w >> 1) & 1, ntsub = w >> 2;
    const int nt = pair * 2 + ntsub;
    const f16* Wd = wih + (size_t)d * G3 * PXKD;
    const int arow = tid >> 2, akc = (tid & 3) * 16;

    f32x4 acc[4][2];
    const f32x4 zz = {0.f, 0.f, 0.f, 0.f};
#pragma unroll
    for (int mi = 0; mi < 4; ++mi)
#pragma unroll
      for (int ni = 0; ni < 2; ++ni) acc[mi][ni] = zz;

    for (int kb = 0; kb < PXKD / 64; ++kb) {
      const int k0 = kb * 64;
      if constexpr (PXF16) {
        const f16* A = (const f16*)pxA;
        const f16* src = A + ((size_t)t * BB + arow) * PXKD + k0 + akc;
        *(f16x8*)&As[arow][akc]     = *(const f16x8*)(src);
        *(f16x8*)&As[arow][akc + 8] = *(const f16x8*)(src + 8);
      } else {
        const float* A = (const float*)pxA;
        const float* src = A + (size_t)arow * (TT * INF) + t * INF + k0 + akc;
#pragma unroll
        for (int p = 0; p < 4; ++p) {
          float4 v = *(const float4*)(src + p * 4);
          f16x4 h4;
          h4[0] = (f16)v.x; h4[1] = (f16)v.y; h4[2] = (f16)v.z; h4[3] = (f16)v.w;
          *(f16x4*)&As[arow][akc + p * 4] = h4;
        }
      }
      {
        const f16* srcb = Wd + (size_t)(pair * 128 + arow) * PXKD + k0 + akc;
        *(f16x8*)&Bs[arow][akc]     = *(const f16x8*)(srcb);
        *(f16x8*)&Bs[arow][akc + 8] = *(const f16x8*)(srcb + 8);
      }
      __syncthreads();
#pragma unroll
      for (int ks = 0; ks < 2; ++ks)
#pragma unroll
        for (int mi = 0; mi < 4; ++mi) {
          f16x8 av = *(const f16x8*)&As[wm * 64 + mi * 16 + cl][ks * 32 + hi * 8];
#pragma unroll
          for (int ni = 0; ni < 2; ++ni) {
            f16x8 bv = *(const f16x8*)&Bs[ntsub * 64 + wn * 32 + ni * 16 + cl][ks * 32 + hi * 8];
            acc[mi][ni] = MF(av, bv, acc[mi][ni]);
          }
        }
      __syncthreads();
    }

    float bias[2], scale[2];
#pragma unroll
    for (int ni = 0; ni < 2; ++ni) {
      int col = nt * 64 + wn * 32 + ni * 16 + cl;
      if (col < 2 * HH) { scale[ni] = SR; bias[ni] = bih[d * G3 + col] + bhhpx[d * G3 + col]; }
      else              { scale[ni] = SN; bias[ni] = bih[d * G3 + col]; }
    }
#pragma unroll
    for (int mi = 0; mi < 4; ++mi)
#pragma unroll
      for (int ni = 0; ni < 2; ++ni)
#pragma unroll
        for (int r = 0; r < 4; ++r) {
          int brow = wm * 64 + mi * 16 + hi * 4 + r;
          int col = nt * 64 + wn * 32 + ni * 16 + cl;
          int g = col >> 8, ch = col & 255;
          size_t slab = (size_t)((d * TC + mt) * 8 + (brow >> 4)) * SLAB;
          int off = ((ch >> 5) * 64 + ((brow & 15) >> 2) * 16 + (ch & 15)) * 24 +
                    (g * 2 + ((ch >> 4) & 1)) * 4 + (brow & 3);
          pxout[slab + off] = (f16)(scale[ni] * (acc[mi][ni][r] + bias[ni]));
        }
  }
}

__global__ void head(const float* __restrict__ hstate, const float* __restrict__ wout,
                     const float* __restrict__ bout, float* __restrict__ out) {
  int g = blockIdx.x * blockDim.x + threadIdx.x;
  if (g >= BB * 4) return;
  int b = g >> 2, o = g & 3;
  float s = bout[o];
  for (int jj = 0; jj < DD2; ++jj) {
    int dd = jj >> 8, j = jj & 255;
    s += hstate[((size_t)dd * BB + b) * HH + j] * wout[o * DD2 + jj];
  }
  out[g] = s;
}

extern "C" void kernel_launch(void* const* d_in, const int* in_sizes, int n_in,
                              void* d_out, int out_size, void* d_ws, size_t ws_size,
                              hipStream_t stream) {
  const float* data = (const float*)d_in[0];
  const float* wih0 = (const float*)d_in[1];
  const float* whh0 = (const float*)d_in[2];
  const float* bih0 = (const float*)d_in[3];
  const float* bhh0 = (const float*)d_in[4];
  const float* wih1 = (const float*)d_in[5];
  const float* whh1 = (const float*)d_in[6];
  const float* bih1 = (const float*)d_in[7];
  const float* bhh1 = (const float*)d_in[8];
  const float* wout = (const float*)d_in[9];
  const float* bout = (const float*)d_in[10];

  char* ws = (char*)d_ws;
  f16*   f_wih0 = (f16*)(ws + 0);
  f16*   f_whh0 = (f16*)(ws + 393216);
  f16*   f_wih1 = (f16*)(ws + 1179648);
  f16*   f_whh1 = (f16*)(ws + 2752512);
  float* hstate = (float*)(ws + 3538944);
  f16*   y0     = (f16*)(ws + 4194304);     // 134217728 B  [T][B][512]
  f16*   pxr    = (f16*)(ws + 138412032);   // 2 ring slots x 25165824 B
  // total 188743680 B

  f16* slot[2] = {pxr, pxr + PXCHUNK};

  convw<<<512, 256, 0, stream>>>(wih0, whh0, wih1, whh1, f_wih0, f_whh0, f_wih1, f_whh1);

  // ---- layer 0 ----
  fused<0, INF, false, false, 40960><<<NPXB, 512, 0, stream>>>(
      nullptr, slot[0], f_whh0, bhh0, hstate, y0, data, f_wih0, bih0, bhh0, 0, 0);
  for (int c = 0; c < NCH; ++c) {
    int npx = (c + 1 < NCH) ? NPXB : 0;
    fused<0, INF, false, true, 86016><<<16 + npx, 512, 0, stream>>>(
        slot[c & 1], slot[(c + 1) & 1], f_whh0, bhh0, hstate, y0,
        data, f_wih0, bih0, bhh0, c, c + 1);
  }
  // ---- layer 1 ----
  fused<1, DD2, true, false, 40960><<<NPXB, 512, 0, stream>>>(
      nullptr, slot[0], f_whh1, bhh1, hstate, nullptr, y0, f_wih1, bih1, bhh1, 0, 0);
  for (int c = 0; c < NCH; ++c) {
    int npx = (c + 1 < NCH) ? NPXB : 0;
    fused<1, DD2, true, true, 86016><<<16 + npx, 512, 0, stream>>>(
        slot[c & 1], slot[(c + 1) & 1], f_whh1, bhh1, hstate, nullptr,
        y0, f_wih1, bih1, bhh1, c, c + 1);
  }
  head<<<4, 128, 0, stream>>>(hstate, wout, bout, (float*)d_out);
}